// Round 6
// baseline (1103.873 us; speedup 1.0000x reference)
//
#include <hip/hip_runtime.h>

// Problem constants
#define DIMC 1024
#define SEQL 2048
#define NB   2
#define NH   16
#define HD   64
#define MTOT (NB*SEQL)          // 4096 rows
#define XSTR 2048               // x rows reused as [q(1024) | k(1024)] bf16, stride in elems
#define LDA  1032               // LDS A-tile leading dim (1024 + 8 pad), 16B-aligned rows
static constexpr float SM_SCALE = 0.125f;             // HEAD_DIM^-0.5
static constexpr float LOG2E    = 1.4426950408889634f;

typedef short s16x8 __attribute__((ext_vector_type(8)));
typedef short s16x4 __attribute__((ext_vector_type(4)));
typedef float f32x4 __attribute__((ext_vector_type(4)));

__device__ __forceinline__ unsigned short f2bf(float f) {
    unsigned int u = __float_as_uint(f);
    u += 0x7fffu + ((u >> 16) & 1u);   // round-to-nearest-even
    return (unsigned short)(u >> 16);
}
__device__ __forceinline__ s16x8 ld8(const unsigned short* p) {
    return *(const s16x8*)p;           // 16B global_load_dwordx4 (bf16 x8)
}
// 8 contiguous fp32 -> bf16x8 fragment (inline cast, RNE)
__device__ __forceinline__ s16x8 ldw8(const float* p) {
    const float4 f0 = *(const float4*)p;
    const float4 f1 = *(const float4*)(p + 4);
    s16x8 o;
    o[0] = (short)f2bf(f0.x); o[1] = (short)f2bf(f0.y);
    o[2] = (short)f2bf(f0.z); o[3] = (short)f2bf(f0.w);
    o[4] = (short)f2bf(f1.x); o[5] = (short)f2bf(f1.y);
    o[6] = (short)f2bf(f1.z); o[7] = (short)f2bf(f1.w);
    return o;
}

// ---------------------------------------------------------------------------
// Fused QKV projection. Block = 256 threads (4 waves) owns 16 rows of x.
// 1) stage 16x1024 fp32 x-rows -> bf16 LDS (block reads ONLY its own rows)
// 2) for p in {q,k,v}: NT GEMM vs fp32 W (inline-cast fragments) + fp32 bias
//    q -> xout[row*XSTR + col]          (over x's own bytes; race-free)
//    k -> xout[row*XSTR + 1024 + col]
//    v -> vtb[((b*NH+h)*HD+d)*SEQL + l] (V^T staged in d_out's first 8MB)
// xf and xout alias -> no __restrict__ on them.
// ---------------------------------------------------------------------------
__global__ __launch_bounds__(256) void fused_qkv(
    const float* xf,
    const float* __restrict__ Wq, const float* __restrict__ bq,
    const float* __restrict__ Wk, const float* __restrict__ bk,
    const float* __restrict__ Wv, const float* __restrict__ bv,
    unsigned short* xout,
    unsigned short* __restrict__ vtb)
{
    __shared__ __align__(16) unsigned short As[16 * LDA];   // 33 KB

    const int t    = threadIdx.x;
    const int lane = t & 63;
    const int l15  = lane & 15;
    const int quad = lane >> 4;
    const int w    = t >> 6;                 // wave id 0..3
    const int row0 = blockIdx.x * 16;

    // stage + cast: one row per pass, 256 float4s per row (one per thread)
#pragma unroll
    for (int r = 0; r < 16; ++r) {
        float4 f = ((const float4*)(xf + (size_t)(row0 + r) * DIMC))[t];
        s16x4 o4;
        o4[0] = (short)f2bf(f.x); o4[1] = (short)f2bf(f.y);
        o4[2] = (short)f2bf(f.z); o4[3] = (short)f2bf(f.w);
        *(s16x4*)(As + r * LDA + t * 4) = o4;
    }
    __syncthreads();

    const float* Ws[3] = { Wq, Wk, Wv };
    const float* Bs[3] = { bq, bk, bv };
    const int colbase = w * 256;             // wave's 256 output cols

    for (int p = 0; p < 3; ++p) {
        const float* wp = Ws[p] + (size_t)(colbase + l15) * DIMC + quad * 8;

        f32x4 acc[16] = {};
        for (int k0 = 0; k0 < DIMC; k0 += 32) {
            s16x8 a = *(const s16x8*)(As + l15 * LDA + k0 + quad * 8);
#pragma unroll
            for (int c = 0; c < 16; ++c) {
                s16x8 b = ldw8(wp + (size_t)c * 16 * DIMC + k0);
                acc[c] = __builtin_amdgcn_mfma_f32_16x16x32_bf16(a, b, acc[c], 0, 0, 0);
            }
        }
#pragma unroll
        for (int c = 0; c < 16; ++c) {
            float bv_ = Bs[p][colbase + c * 16 + l15];   // fp32 bias, exact add
#pragma unroll
            for (int r = 0; r < 4; ++r) acc[c][r] += bv_;
        }

        if (p < 2) {
            // q (p=0) / k (p=1) interleaved into x's own rows
            const int off = p * DIMC;
#pragma unroll
            for (int c = 0; c < 16; ++c) {
                const int col = colbase + c * 16 + l15;
#pragma unroll
                for (int r = 0; r < 4; ++r) {
                    const int row = row0 + quad * 4 + r;
                    xout[(size_t)row * XSTR + off + col] = f2bf(acc[c][r]);
                }
            }
        } else {
            // V^T store: lane's 4 values are consecutive in l -> 8B store
#pragma unroll
            for (int c = 0; c < 16; ++c) {
                const int col = colbase + c * 16 + l15;    // o = h*HD + d
                const int h = col >> 6, d = col & 63;
                const int lidx = row0 + quad * 4;
                const int bb = lidx >> 11;                 // / SEQL
                const int ll = lidx & (SEQL - 1);
                s16x4 v4;
                v4[0] = (short)f2bf(acc[c][0]);
                v4[1] = (short)f2bf(acc[c][1]);
                v4[2] = (short)f2bf(acc[c][2]);
                v4[3] = (short)f2bf(acc[c][3]);
                *(s16x4*)(vtb + ((size_t)((bb * NH + h) * HD + d)) * SEQL + ll) = v4;
            }
        }
    }
}

// ---------------------------------------------------------------------------
// Flash attention: one wave per (b, h, 16-row Q tile). q at xqk[row*XSTR+...],
// k at xqk[row*XSTR+1024+...]. O written in-place over the q slots (disjoint
// per block). v: (B,H,HD,L) bf16 in vt.
// ---------------------------------------------------------------------------
__global__ __launch_bounds__(64) void attn_fused(
    unsigned short* xqk,
    const unsigned short* __restrict__ vt)
{
    __shared__ __align__(16) unsigned short pbuf[16 * 32];

    const int lane = threadIdx.x;
    const int l15  = lane & 15;
    const int quad = lane >> 4;

    const int qtiles = SEQL / 16;            // 128
    const int qt = blockIdx.x % qtiles;
    const int bh = blockIdx.x / qtiles;      // b*NH + h
    const int h  = bh % NH;
    const int bb = bh / NH;
    const int q0 = qt * 16;

    // Q A-fragments (two 32-wide k-chunks covering D=64), loaded before any store
    unsigned short* qrow = xqk + (size_t)(bb * SEQL + q0 + l15) * XSTR + h * HD + quad * 8;
    const s16x8 aq0 = ld8(qrow);
    const s16x8 aq1 = ld8(qrow + 32);

    const unsigned short* kbase = xqk + (size_t)bb * SEQL * XSTR + DIMC + h * HD + quad * 8;
    const unsigned short* vbase = vt + (size_t)(bh * HD) * SEQL + quad * 8;

    float mrow[4], lrow[4];
#pragma unroll
    for (int r = 0; r < 4; ++r) { mrow[r] = -1e30f; lrow[r] = 0.f; }
    f32x4 o[4] = {};

    for (int j0 = 0; j0 < SEQL; j0 += 32) {
        // S = Q K^T for 32 keys -> two 16x16 C-frags
        f32x4 s0 = {}, s1 = {};
        {
            const unsigned short* kr0 = kbase + (size_t)(j0 + l15) * XSTR;
            const unsigned short* kr1 = kbase + (size_t)(j0 + 16 + l15) * XSTR;
            s16x8 b00 = ld8(kr0), b10 = ld8(kr0 + 32);
            s16x8 b01 = ld8(kr1), b11 = ld8(kr1 + 32);
            s0 = __builtin_amdgcn_mfma_f32_16x16x32_bf16(aq0, b00, s0, 0, 0, 0);
            s0 = __builtin_amdgcn_mfma_f32_16x16x32_bf16(aq1, b10, s0, 0, 0, 0);
            s1 = __builtin_amdgcn_mfma_f32_16x16x32_bf16(aq0, b01, s1, 0, 0, 0);
            s1 = __builtin_amdgcn_mfma_f32_16x16x32_bf16(aq1, b11, s1, 0, 0, 0);
        }

        // online softmax per C/D row (row = quad*4+r, cols spread over 16 lanes)
        float p0[4], p1[4], alpha[4];
#pragma unroll
        for (int r = 0; r < 4; ++r) {
            float v0 = s0[r] * SM_SCALE, v1 = s1[r] * SM_SCALE;
            float mx = fmaxf(v0, v1);
            mx = fmaxf(mx, __shfl_xor(mx, 1));
            mx = fmaxf(mx, __shfl_xor(mx, 2));
            mx = fmaxf(mx, __shfl_xor(mx, 4));
            mx = fmaxf(mx, __shfl_xor(mx, 8));
            float mn = fmaxf(mrow[r], mx);
            float a  = exp2f((mrow[r] - mn) * LOG2E);
            p0[r] = exp2f((v0 - mn) * LOG2E);
            p1[r] = exp2f((v1 - mn) * LOG2E);
            float sum = p0[r] + p1[r];
            sum += __shfl_xor(sum, 1);
            sum += __shfl_xor(sum, 2);
            sum += __shfl_xor(sum, 4);
            sum += __shfl_xor(sum, 8);
            lrow[r] = lrow[r] * a + sum;
            mrow[r] = mn;
            alpha[r] = a;
        }

        // P: C/D layout -> A-operand layout via LDS round trip (m120 pattern)
#pragma unroll
        for (int r = 0; r < 4; ++r) {
            pbuf[(quad * 4 + r) * 32 + l15]      = f2bf(p0[r]);
            pbuf[(quad * 4 + r) * 32 + 16 + l15] = f2bf(p1[r]);
        }
        __syncthreads();
        s16x8 ap = *(const s16x8*)(pbuf + l15 * 32 + quad * 8);
        __syncthreads();

        // rescale O accumulator, then PV over 4 d-chunks
#pragma unroll
        for (int c = 0; c < 4; ++c)
#pragma unroll
            for (int r = 0; r < 4; ++r) o[c][r] *= alpha[r];

#pragma unroll
        for (int c = 0; c < 4; ++c) {
            s16x8 bv = ld8(vbase + (size_t)(c * 16 + l15) * SEQL + j0);
            o[c] = __builtin_amdgcn_mfma_f32_16x16x32_bf16(ap, bv, o[c], 0, 0, 0);
        }
    }

    // epilogue: normalize by l and store back over the q slots (in-place)
#pragma unroll
    for (int c = 0; c < 4; ++c) {
        const int d = c * 16 + l15;
#pragma unroll
        for (int r = 0; r < 4; ++r) {
            const int qq = q0 + quad * 4 + r;
            xqk[(size_t)(bb * SEQL + qq) * XSTR + h * HD + d] = f2bf(o[c][r] / lrow[r]);
        }
    }
}

// ---------------------------------------------------------------------------
// Output projection: A = attn-out (bf16, stride XSTR, q slots of x),
// W = Wp fp32 (inline cast), out = d_out FP32 row-major (reference output
// dtype is float32 per the harness contract).
// ---------------------------------------------------------------------------
__global__ __launch_bounds__(256) void out_proj(
    const unsigned short* __restrict__ xq,
    const float* __restrict__ Wp, const float* __restrict__ bp,
    float* __restrict__ outf)
{
    __shared__ __align__(16) unsigned short As[16 * LDA];

    const int t    = threadIdx.x;
    const int lane = t & 63;
    const int l15  = lane & 15;
    const int quad = lane >> 4;
    const int w    = t >> 6;
    const int row0 = blockIdx.x * 16;

    // stage 16 rows (bf16, stride XSTR): 2 rows per pass, 8 passes
#pragma unroll
    for (int pass = 0; pass < 8; ++pass) {
        const int r = pass * 2 + (t >> 7);
        const int c = (t & 127) * 8;
        *(s16x8*)(As + r * LDA + c) = ld8(xq + (size_t)(row0 + r) * XSTR + c);
    }
    __syncthreads();

    const int colbase = w * 256;
    const float* wp = Wp + (size_t)(colbase + l15) * DIMC + quad * 8;

    f32x4 acc[16] = {};
    for (int k0 = 0; k0 < DIMC; k0 += 32) {
        s16x8 a = *(const s16x8*)(As + l15 * LDA + k0 + quad * 8);
#pragma unroll
        for (int c = 0; c < 16; ++c) {
            s16x8 b = ldw8(wp + (size_t)c * 16 * DIMC + k0);
            acc[c] = __builtin_amdgcn_mfma_f32_16x16x32_bf16(a, b, acc[c], 0, 0, 0);
        }
    }

#pragma unroll
    for (int c = 0; c < 16; ++c) {
        float bv_ = bp[colbase + c * 16 + l15];
#pragma unroll
        for (int r = 0; r < 4; ++r) acc[c][r] += bv_;
    }

    // fp32 store (output dtype = float32)
#pragma unroll
    for (int c = 0; c < 16; ++c) {
        const int col = colbase + c * 16 + l15;
#pragma unroll
        for (int r = 0; r < 4; ++r) {
            const int row = row0 + quad * 4 + r;
            outf[(size_t)row * DIMC + col] = acc[c][r];
        }
    }
}

// ---------------------------------------------------------------------------
// ZERO d_ws usage. Inputs fp32, OUTPUT FP32 (reference dtype); bf16 internal.
// q,k live in x's own 16MB as interleaved bf16 (in-place, per-block rows);
// V^T staged in d_out's first 8MB (dead before out_proj overwrites d_out);
// attn-out in-place over the q slots. Harness restores d_in before every
// launch, so clobbering x is safe by contract.
// ---------------------------------------------------------------------------
extern "C" void kernel_launch(void* const* d_in, const int* in_sizes, int n_in,
                              void* d_out, int out_size, void* d_ws, size_t ws_size,
                              hipStream_t stream) {
    const float* x  = (const float*)d_in[0];
    const float* Wq = (const float*)d_in[1];
    const float* bq = (const float*)d_in[2];
    const float* Wk = (const float*)d_in[3];
    const float* bk = (const float*)d_in[4];
    const float* Wv = (const float*)d_in[5];
    const float* bv = (const float*)d_in[6];
    const float* Wp = (const float*)d_in[7];
    const float* bp = (const float*)d_in[8];
    float* out = (float*)d_out;                        // FP32 output
    unsigned short* vtb = (unsigned short*)d_out;      // V^T staging (dead later)
    unsigned short* xqk = (unsigned short*)d_in[0];    // aliases x (by design)

    fused_qkv<<<MTOT / 16, 256, 0, stream>>>(x, Wq, bq, Wk, bk, Wv, bv, xqk, vtb);
    attn_fused<<<NB * NH * (SEQL / 16), 64, 0, stream>>>(xqk, vtb);
    out_proj<<<MTOT / 16, 256, 0, stream>>>(xqk, Wp, bp, out);
}

// Round 7
// 404.509 us; speedup vs baseline: 2.7289x; 2.7289x over previous
//
#include <hip/hip_runtime.h>

// Problem constants
#define DIMC 1024
#define SEQL 2048
#define NB   2
#define NH   16
#define HD   64
#define MTOT (NB*SEQL)          // 4096 rows
#define XSTR 2048               // q/k interleaved in x buffer: [q 1024 | k 1024] per row
static constexpr float SM_SCALE = 0.125f;             // HEAD_DIM^-0.5
static constexpr float LOG2E    = 1.4426950408889634f;

typedef short s16x8 __attribute__((ext_vector_type(8)));
typedef short s16x4 __attribute__((ext_vector_type(4)));
typedef float f32x4 __attribute__((ext_vector_type(4)));

__device__ __forceinline__ unsigned short f2bf(float f) {
    unsigned int u = __float_as_uint(f);
    u += 0x7fffu + ((u >> 16) & 1u);   // round-to-nearest-even
    return (unsigned short)(u >> 16);
}
__device__ __forceinline__ s16x8 ld8(const unsigned short* p) {
    return *(const s16x8*)p;           // 16B global_load_dwordx4 (bf16 x8)
}
// async global->LDS, 16B per lane (m97: the 874 TF enabler)
__device__ __forceinline__ void gld_lds16(const unsigned short* g, unsigned short* l) {
    __builtin_amdgcn_global_load_lds(
        (const __attribute__((address_space(1))) void*)g,
        (__attribute__((address_space(3))) void*)l, 16, 0, 0);
}

// ---------------------------------------------------------------------------
// fp32 -> bf16 cast, 4 elements/thread
// ---------------------------------------------------------------------------
__global__ __launch_bounds__(256) void cast_bf16(
    const float* __restrict__ src, unsigned short* __restrict__ dst, int n4)
{
    int i = blockIdx.x * blockDim.x + threadIdx.x;
    if (i < n4) {
        float4 f = ((const float4*)src)[i];
        s16x4 o;
        o[0] = (short)f2bf(f.x); o[1] = (short)f2bf(f.y);
        o[2] = (short)f2bf(f.z); o[3] = (short)f2bf(f.w);
        ((s16x4*)dst)[i] = o;
    }
}

// pack q/k/v biases into one contiguous fp32 array of 3072
__global__ __launch_bounds__(256) void pack_bias(
    const float* __restrict__ b0, const float* __restrict__ b1,
    const float* __restrict__ b2, float* __restrict__ dst)
{
    int t = blockIdx.x * blockDim.x + threadIdx.x;
    if (t < 1024)      dst[t] = b0[t];
    else if (t < 2048) dst[t] = b1[t - 1024];
    else if (t < 3072) dst[t] = b2[t - 2048];
}

// ---------------------------------------------------------------------------
// m97-style 128x128-tile NT GEMM, K=1024, BK=32, 256 threads (2x2 waves of
// 64x64). A: bf16, row stride astride. W: bf16 N x 1024 row-major. Async
// global_load_lds staging (16B/lane), ds_read_b128 fragments, MFMA 16x16x32.
// mode 0 (QKV fused, N=3072): nt 0..7 -> q, 8..15 -> k (interleaved into qk),
//   16..23 -> v^T into vtb (b,h,d,l).   bias indexed [proj*1024 + col].
// mode 1 (out-proj, N=1024): fp32 store to outf, bias[col].
// ---------------------------------------------------------------------------
__global__ __launch_bounds__(256) void gemm_tile(
    const unsigned short* __restrict__ A, int astride,
    const unsigned short* __restrict__ Wb,
    const float* __restrict__ bias,
    unsigned short* qk, unsigned short* vtb, float* outf, int mode)
{
    __shared__ __align__(16) unsigned short Asm[128 * 32];   // 8 KB
    __shared__ __align__(16) unsigned short Bsm[128 * 32];   // 8 KB

    const int t    = threadIdx.x;
    const int lane = t & 63;
    const int l15  = lane & 15;
    const int quad = lane >> 4;
    const int w    = t >> 6;
    const int mrow = (w & 1) * 64;
    const int ncol = (w >> 1) * 64;
    const int mt   = blockIdx.x & 31;
    const int nt   = blockIdx.x >> 5;
    const int row0 = mt * 128;

    // staging source pointers: thread t covers row t>>2 (and +64), col (t&3)*8
    const unsigned short* ga = A  + (size_t)(row0 + (t >> 2)) * astride + (t & 3) * 8;
    const unsigned short* gb = Wb + (size_t)(nt * 128 + (t >> 2)) * DIMC + (t & 3) * 8;
    const size_t gaStep = (size_t)64 * astride;
    const size_t gbStep = (size_t)64 * DIMC;

    f32x4 acc[4][4] = {};

    for (int k0 = 0; k0 < DIMC; k0 += 32) {
        // async stage: LDS layout row-major [128][32], lds = base + t*16B
        gld_lds16(ga + k0,          Asm + t * 8);
        gld_lds16(ga + gaStep + k0, Asm + 2048 + t * 8);
        gld_lds16(gb + k0,          Bsm + t * 8);
        gld_lds16(gb + gbStep + k0, Bsm + 2048 + t * 8);
        __syncthreads();                       // drains vmcnt + barrier

        s16x8 a[4], b[4];
#pragma unroll
        for (int mi = 0; mi < 4; ++mi)
            a[mi] = *(const s16x8*)(Asm + (mrow + mi * 16 + l15) * 32 + quad * 8);
#pragma unroll
        for (int ni = 0; ni < 4; ++ni)
            b[ni] = *(const s16x8*)(Bsm + (ncol + ni * 16 + l15) * 32 + quad * 8);
#pragma unroll
        for (int mi = 0; mi < 4; ++mi)
#pragma unroll
            for (int ni = 0; ni < 4; ++ni)
                acc[mi][ni] = __builtin_amdgcn_mfma_f32_16x16x32_bf16(
                    a[mi], b[ni], acc[mi][ni], 0, 0, 0);
        __syncthreads();
    }

    // epilogue
    const int proj = nt >> 3;                  // mode0: 0/1/2 ; mode1: 0
#pragma unroll
    for (int ni = 0; ni < 4; ++ni) {
        const int cq = (nt & 7) * 128 + ncol + ni * 16 + l15;   // col within proj
        const float bz = bias[proj * 1024 + cq];
#pragma unroll
        for (int mi = 0; mi < 4; ++mi) {
            const int rbase = row0 + mrow + mi * 16 + quad * 4;
            if (mode == 0) {
                if (proj < 2) {
#pragma unroll
                    for (int r = 0; r < 4; ++r)
                        qk[(size_t)(rbase + r) * XSTR + proj * DIMC + cq] =
                            f2bf(acc[mi][ni][r] + bz);
                } else {
                    const int h = cq >> 6, d = cq & 63;
                    const int bb = rbase >> 11, ll = rbase & (SEQL - 1);
                    s16x4 v4;
                    v4[0] = (short)f2bf(acc[mi][ni][0] + bz);
                    v4[1] = (short)f2bf(acc[mi][ni][1] + bz);
                    v4[2] = (short)f2bf(acc[mi][ni][2] + bz);
                    v4[3] = (short)f2bf(acc[mi][ni][3] + bz);
                    *(s16x4*)(vtb + ((size_t)((bb * NH + h) * HD + d)) * SEQL + ll) = v4;
                }
            } else {
#pragma unroll
                for (int r = 0; r < 4; ++r)
                    outf[(size_t)(rbase + r) * DIMC + cq] = acc[mi][ni][r] + bz;
            }
        }
    }
}

// ---------------------------------------------------------------------------
// Flash attention (unchanged from round 6 pass): one wave per (b,h,16-row
// Q-tile); q at xqk[row*XSTR], k at +1024; O in-place over q slots.
// v: (B,H,HD,L) bf16.
// ---------------------------------------------------------------------------
__global__ __launch_bounds__(64) void attn_fused(
    unsigned short* xqk,
    const unsigned short* __restrict__ vt)
{
    __shared__ __align__(16) unsigned short pbuf[16 * 32];

    const int lane = threadIdx.x;
    const int l15  = lane & 15;
    const int quad = lane >> 4;

    const int qtiles = SEQL / 16;            // 128
    const int qt = blockIdx.x % qtiles;
    const int bh = blockIdx.x / qtiles;
    const int h  = bh % NH;
    const int bb = bh / NH;
    const int q0 = qt * 16;

    unsigned short* qrow = xqk + (size_t)(bb * SEQL + q0 + l15) * XSTR + h * HD + quad * 8;
    const s16x8 aq0 = ld8(qrow);
    const s16x8 aq1 = ld8(qrow + 32);

    const unsigned short* kbase = xqk + (size_t)bb * SEQL * XSTR + DIMC + h * HD + quad * 8;
    const unsigned short* vbase = vt + (size_t)(bh * HD) * SEQL + quad * 8;

    float mrow[4], lrow[4];
#pragma unroll
    for (int r = 0; r < 4; ++r) { mrow[r] = -1e30f; lrow[r] = 0.f; }
    f32x4 o[4] = {};

    for (int j0 = 0; j0 < SEQL; j0 += 32) {
        f32x4 s0 = {}, s1 = {};
        {
            const unsigned short* kr0 = kbase + (size_t)(j0 + l15) * XSTR;
            const unsigned short* kr1 = kbase + (size_t)(j0 + 16 + l15) * XSTR;
            s16x8 b00 = ld8(kr0), b10 = ld8(kr0 + 32);
            s16x8 b01 = ld8(kr1), b11 = ld8(kr1 + 32);
            s0 = __builtin_amdgcn_mfma_f32_16x16x32_bf16(aq0, b00, s0, 0, 0, 0);
            s0 = __builtin_amdgcn_mfma_f32_16x16x32_bf16(aq1, b10, s0, 0, 0, 0);
            s1 = __builtin_amdgcn_mfma_f32_16x16x32_bf16(aq0, b01, s1, 0, 0, 0);
            s1 = __builtin_amdgcn_mfma_f32_16x16x32_bf16(aq1, b11, s1, 0, 0, 0);
        }

        float p0[4], p1[4], alpha[4];
#pragma unroll
        for (int r = 0; r < 4; ++r) {
            float v0 = s0[r] * SM_SCALE, v1 = s1[r] * SM_SCALE;
            float mx = fmaxf(v0, v1);
            mx = fmaxf(mx, __shfl_xor(mx, 1));
            mx = fmaxf(mx, __shfl_xor(mx, 2));
            mx = fmaxf(mx, __shfl_xor(mx, 4));
            mx = fmaxf(mx, __shfl_xor(mx, 8));
            float mn = fmaxf(mrow[r], mx);
            float a  = exp2f((mrow[r] - mn) * LOG2E);
            p0[r] = exp2f((v0 - mn) * LOG2E);
            p1[r] = exp2f((v1 - mn) * LOG2E);
            float sum = p0[r] + p1[r];
            sum += __shfl_xor(sum, 1);
            sum += __shfl_xor(sum, 2);
            sum += __shfl_xor(sum, 4);
            sum += __shfl_xor(sum, 8);
            lrow[r] = lrow[r] * a + sum;
            mrow[r] = mn;
            alpha[r] = a;
        }

#pragma unroll
        for (int r = 0; r < 4; ++r) {
            pbuf[(quad * 4 + r) * 32 + l15]      = f2bf(p0[r]);
            pbuf[(quad * 4 + r) * 32 + 16 + l15] = f2bf(p1[r]);
        }
        __syncthreads();
        s16x8 ap = *(const s16x8*)(pbuf + l15 * 32 + quad * 8);
        __syncthreads();

#pragma unroll
        for (int c = 0; c < 4; ++c)
#pragma unroll
            for (int r = 0; r < 4; ++r) o[c][r] *= alpha[r];

#pragma unroll
        for (int c = 0; c < 4; ++c) {
            s16x8 bv = ld8(vbase + (size_t)(c * 16 + l15) * SEQL + j0);
            o[c] = __builtin_amdgcn_mfma_f32_16x16x32_bf16(ap, bv, o[c], 0, 0, 0);
        }
    }

#pragma unroll
    for (int c = 0; c < 4; ++c) {
        const int d = c * 16 + l15;
#pragma unroll
        for (int r = 0; r < 4; ++r) {
            const int qq = q0 + quad * 4 + r;
            xqk[(size_t)(bb * SEQL + qq) * XSTR + h * HD + d] = f2bf(o[c][r] / lrow[r]);
        }
    }
}

// ---------------------------------------------------------------------------
// ws (>=24MB proven by R4/R5 bit-identical evidence) layout, u16 elems:
//   xb   [0, 4M)      x cast to bf16 (8 MB)
//   wall [4M, 8M)     Wq|Wk|Wv|Wp bf16 (8 MB)
//   ball fp32 3072 @ byte 16M (12 KB)
// q,k -> x's buffer (fp32 x dead after cast); V^T -> d_out (dead before
// out-proj); attn-out in-place over q slots; final out fp32 -> d_out.
// ---------------------------------------------------------------------------
extern "C" void kernel_launch(void* const* d_in, const int* in_sizes, int n_in,
                              void* d_out, int out_size, void* d_ws, size_t ws_size,
                              hipStream_t stream) {
    const float* x  = (const float*)d_in[0];
    const float* Wq = (const float*)d_in[1];
    const float* bq = (const float*)d_in[2];
    const float* Wk = (const float*)d_in[3];
    const float* bk = (const float*)d_in[4];
    const float* Wv = (const float*)d_in[5];
    const float* bv = (const float*)d_in[6];
    const float* Wp = (const float*)d_in[7];
    const float* bp = (const float*)d_in[8];
    float* out = (float*)d_out;
    unsigned short* vtb = (unsigned short*)d_out;
    unsigned short* xqk = (unsigned short*)d_in[0];

    unsigned short* ws   = (unsigned short*)d_ws;
    const size_t XELT = (size_t)MTOT * DIMC;     // 4M
    const size_t WELT = (size_t)DIMC * DIMC;     // 1M
    unsigned short* xb   = ws;
    unsigned short* wall = ws + XELT;
    float*          ball = (float*)(ws + 2 * XELT);

    cast_bf16<<<XELT / 4 / 256, 256, 0, stream>>>(x,  xb,            XELT / 4);
    cast_bf16<<<WELT / 4 / 256, 256, 0, stream>>>(Wq, wall,          WELT / 4);
    cast_bf16<<<WELT / 4 / 256, 256, 0, stream>>>(Wk, wall + WELT,   WELT / 4);
    cast_bf16<<<WELT / 4 / 256, 256, 0, stream>>>(Wv, wall + 2*WELT, WELT / 4);
    cast_bf16<<<WELT / 4 / 256, 256, 0, stream>>>(Wp, wall + 3*WELT, WELT / 4);
    pack_bias<<<12, 256, 0, stream>>>(bq, bk, bv, ball);

    // fused QKV GEMM: M=4096, N=3072 -> 32 x 24 tiles = 768 blocks (3/CU)
    gemm_tile<<<768, 256, 0, stream>>>(xb, DIMC, wall, ball, xqk, vtb, nullptr, 0);

    attn_fused<<<NB * NH * (SEQL / 16), 64, 0, stream>>>(xqk, vtb);

    // out-proj: M=4096, N=1024 -> 32 x 8 = 256 blocks, fp32 out
    gemm_tile<<<256, 256, 0, stream>>>(xqk, XSTR, wall + 3 * WELT, bp,
                                       nullptr, nullptr, out, 1);
}